// Round 10
// baseline (482.252 us; speedup 1.0000x reference)
//
#include <hip/hip_runtime.h>

#define NKV 8192
#define NB 64

typedef __attribute__((ext_vector_type(8))) short short8;
typedef __attribute__((ext_vector_type(8))) unsigned short ushort8;
typedef __attribute__((ext_vector_type(4))) unsigned short usx4;
typedef __attribute__((ext_vector_type(4))) float f32x4;

__device__ __forceinline__ float bf2f(unsigned short u) {
  return __uint_as_float(((unsigned int)u) << 16);
}
__device__ __forceinline__ unsigned short f2bf(float f) {
  unsigned int x = __float_as_uint(f);
  return (unsigned short)((x + 0x7fffu + ((x >> 16) & 1u)) >> 16);
}
__device__ __forceinline__ float sigm(float x) { return 1.f / (1.f + __expf(-x)); }

// ---------------------------------------------------------------------------
// K0 (fused): wf fragments for Wk/Wv  +  GRU weight transpose.
// grid 52 x 256 (1024 wf threads + 12288 transpose threads).
// ---------------------------------------------------------------------------
__global__ __launch_bounds__(256) void k_prep0(
    const float* __restrict__ Wk, const float* __restrict__ Wv,
    const float* __restrict__ W_ih, const float* __restrict__ W_hh,
    unsigned short* __restrict__ wf,
    float* __restrict__ WihT, float* __restrict__ WhhT) {
  int idx = blockIdx.x * 256 + threadIdx.x;
  if (idx < 1024) {
    int lane = idx & 63, ct = (idx >> 6) & 7, kf = idx >> 9;
    int half = lane >> 4, rlo = lane & 15;
    const float* W = (ct < 4) ? Wk : Wv;
    int cc = (ct & 3) * 16 + rlo;
    ushort8 pk;
#pragma unroll
    for (int i = 0; i < 8; ++i)
      pk[i] = f2bf(W[(kf * 32 + half * 8 + i) * 64 + cc]);
    *(ushort8*)(wf + (size_t)idx * 8) = pk;
  } else if (idx < 1024 + 192 * 64) {
    int k = idx - 1024;
    int o = k >> 6, j = k & 63;
    WihT[j * 192 + o] = W_ih[k];
    WhhT[j * 192 + o] = W_hh[k];
  }
}

// ---------------------------------------------------------------------------
// K1: LN + k/v projection over HALF the tokens (tokbase selects half).
// grid 2048 x 256; 2 tiles of 16 tokens per wave.
// ---------------------------------------------------------------------------
__global__ __launch_bounds__(256) void k_proj(
    const float* __restrict__ x, const float* __restrict__ gin,
    const float* __restrict__ bin, const unsigned short* __restrict__ wf,
    unsigned short* __restrict__ kv, long tokbase) {
  const int lane = threadIdx.x & 63;
  const int wave = threadIdx.x >> 6;
  const int half = lane >> 4, rlo = lane & 15;

  short8 bfr[2][8];
  const ushort8* wf8 = (const ushort8*)wf;
#pragma unroll
  for (int kf = 0; kf < 2; ++kf)
#pragma unroll
    for (int ct = 0; ct < 8; ++ct)
      bfr[kf][ct] = (short8)wf8[(kf * 8 + ct) * 64 + lane];

  float g0[8], g1[8], bb0[8], bb1[8];
#pragma unroll
  for (int i = 0; i < 8; ++i) {
    g0[i] = gin[half * 8 + i];      bb0[i] = bin[half * 8 + i];
    g1[i] = gin[32 + half * 8 + i]; bb1[i] = bin[32 + half * 8 + i];
  }
  long tok0 = tokbase + ((long)blockIdx.x * 4 + wave) * 32;
#pragma unroll
  for (int tile = 0; tile < 2; ++tile) {
    long row = tok0 + tile * 16 + rlo;
    const f32x4* p4 = (const f32x4*)(x + row * 64);
    f32x4 u0 = p4[half * 2], u1 = p4[half * 2 + 1];
    f32x4 u2 = p4[8 + half * 2], u3 = p4[9 + half * 2];
    float s = 0.f, ss = 0.f;
#pragma unroll
    for (int i = 0; i < 4; ++i) {
      s += u0[i] + u1[i] + u2[i] + u3[i];
      ss = fmaf(u0[i], u0[i], fmaf(u1[i], u1[i], fmaf(u2[i], u2[i], fmaf(u3[i], u3[i], ss))));
    }
    s += __shfl_xor(s, 16); ss += __shfl_xor(ss, 16);
    s += __shfl_xor(s, 32); ss += __shfl_xor(ss, 32);
    float m = s * 0.015625f;
    float var = ss * 0.015625f - m * m;
    float rs = rsqrtf(var + 1e-5f);
    short8 a0, a1;
#pragma unroll
    for (int i = 0; i < 4; ++i) {
      a0[i]     = (short)f2bf((u0[i] - m) * rs * g0[i]     + bb0[i]);
      a0[i + 4] = (short)f2bf((u1[i] - m) * rs * g0[i + 4] + bb0[i + 4]);
      a1[i]     = (short)f2bf((u2[i] - m) * rs * g1[i]     + bb1[i]);
      a1[i + 4] = (short)f2bf((u3[i] - m) * rs * g1[i + 4] + bb1[i + 4]);
    }
    long t = tok0 + tile * 16 + rlo;
#pragma unroll
    for (int ct = 0; ct < 8; ++ct) {
      f32x4 acc = {0.f, 0.f, 0.f, 0.f};
      acc = __builtin_amdgcn_mfma_f32_16x16x32_bf16(bfr[0][ct], a0, acc, 0, 0, 0);
      acc = __builtin_amdgcn_mfma_f32_16x16x32_bf16(bfr[1][ct], a1, acc, 0, 0, 0);
      float sc = (ct < 4) ? 0.25f : 1.f;
      usx4 pk;
#pragma unroll
      for (int r = 0; r < 4; ++r) pk[r] = f2bf(acc[r] * sc);
      *(usx4*)(kv + t * 128 + ct * 16 + half * 4) = pk;
    }
  }
}

// ---------------------------------------------------------------------------
// K_prep: one wave per (batch,slot). grid 512 x 64.
// ---------------------------------------------------------------------------
__global__ __launch_bounds__(64) void k_prep(
    const float* __restrict__ slots_in, const float* __restrict__ g_slot,
    const float* __restrict__ b_slot, const float* __restrict__ Wq,
    float* __restrict__ slots_buf, float* __restrict__ qbuf,
    float* __restrict__ Sg, float* __restrict__ Wg) {
  int b = blockIdx.x >> 3, s = blockIdx.x & 7, d = threadIdx.x;
  __shared__ float l2_s[64];
  float x = slots_in[(b * 8 + s) * 64 + d];
  slots_buf[(b * 8 + s) * 64 + d] = x;
  float sum = x, sq = x * x;
#pragma unroll
  for (int msk = 1; msk < 64; msk <<= 1) { sum += __shfl_xor(sum, msk); sq += __shfl_xor(sq, msk); }
  float mean = sum * 0.015625f, var = sq * 0.015625f - mean * mean;
  float ln = (x - mean) * rsqrtf(var + 1e-5f) * g_slot[d] + b_slot[d];
  l2_s[d] = ln;
  __syncthreads();
  float acc = 0.f;
#pragma unroll 8
  for (int j = 0; j < 64; ++j) acc = fmaf(l2_s[j], Wq[j * 64 + d], acc);
  acc *= 0.25f;
  int hh = d >> 4, dh = d & 15, hq = hh * 8 + s;
  qbuf[(b * 32 + hq) * 16 + dh] = acc;
  if (d < 4) Sg[b * 32 + d * 8 + s] = 0.f;
  Wg[(b * 32 + hq) * 16 + dh] = 0.f;
}

// ---------------------------------------------------------------------------
// K2: per wave 64 tokens. Q A-fragments built in-register from qbuf
// (block-diagonal: per (m,kc) chunk either zero or 8 consecutive floats).
// V staged in LDS; QK 4 MFMA/tile; softmax shfl(16,32); PV 16 MFMA.
// grid (B*32) x 256.
// ---------------------------------------------------------------------------
template <int IT>
__global__ __launch_bounds__(256) void k_attn(
    const unsigned short* __restrict__ kv, const float* __restrict__ qbuf,
    float* __restrict__ Sg, float* __restrict__ Wg,
    float* __restrict__ vis) {
  constexpr bool last = (IT == 2);
  int b = blockIdx.x >> 5, chunk = blockIdx.x & 31;
  int lane = threadIdx.x & 63, wave = threadIdx.x >> 6;
  int half = lane >> 4, rlo = lane & 15;
  __shared__ unsigned short P[4][64 * 34];   // reused as Wred (f32[512])
  __shared__ unsigned short Vs[4][64 * 66];
  int t0 = chunk * 256 + wave * 64;
  long gbase = ((long)(b * NKV) + t0) * 128;

  // stage V coalesced
  {
    int vtok = lane >> 3, vcol = (lane & 7) * 8;
#pragma unroll
    for (int r = 0; r < 8; ++r) {
      int tr = r * 8 + vtok;
      ushort8 vv = *(const ushort8*)(kv + gbase + (long)tr * 128 + 64 + vcol);
      *(ushort8*)(&Vs[wave][tr * 66 + vcol]) = vv;
    }
  }

  // Q fragments in-register (block-diagonal)
  short8 afr[2][2];
#pragma unroll
  for (int m = 0; m < 2; ++m) {
    int hq = m * 16 + rlo, h = hq >> 3;
#pragma unroll
    for (int kc = 0; kc < 2; ++kc) {
      short8 f = {0, 0, 0, 0, 0, 0, 0, 0};
      if (kc * 2 + (half >> 1) == h) {
        const float* qp = qbuf + (b * 32 + hq) * 16 + (half & 1) * 8;
#pragma unroll
        for (int i = 0; i < 8; ++i) f[i] = (short)f2bf(qp[i]);
      }
      afr[m][kc] = f;
    }
  }

  float Sacc[2][4];
#pragma unroll
  for (int m = 0; m < 2; ++m)
#pragma unroll
    for (int r = 0; r < 4; ++r) Sacc[m][r] = 0.f;

#pragma unroll
  for (int nt = 0; nt < 4; ++nt) {
    long rowb = gbase + (long)(nt * 16 + rlo) * 128;
    short8 bk0 = *(const short8*)(kv + rowb + half * 8);
    short8 bk1 = *(const short8*)(kv + rowb + 32 + half * 8);
    f32x4 acc0 = {0.f, 0.f, 0.f, 0.f}, acc1 = {0.f, 0.f, 0.f, 0.f};
    acc0 = __builtin_amdgcn_mfma_f32_16x16x32_bf16(afr[0][0], bk0, acc0, 0, 0, 0);
    acc0 = __builtin_amdgcn_mfma_f32_16x16x32_bf16(afr[0][1], bk1, acc0, 0, 0, 0);
    acc1 = __builtin_amdgcn_mfma_f32_16x16x32_bf16(afr[1][0], bk0, acc1, 0, 0, 0);
    acc1 = __builtin_amdgcn_mfma_f32_16x16x32_bf16(afr[1][1], bk1, acc1, 0, 0, 0);
    float e0[4], e1[4], ssum = 0.f;
#pragma unroll
    for (int r = 0; r < 4; ++r) {
      e0[r] = __expf(acc0[r]); e1[r] = __expf(acc1[r]);
      ssum += e0[r] + e1[r];
    }
    ssum += __shfl_xor(ssum, 16);
    ssum += __shfl_xor(ssum, 32);
    float rs = __builtin_amdgcn_rcpf(ssum);
    float a0[4], a1[4];
#pragma unroll
    for (int r = 0; r < 4; ++r) {
      a0[r] = e0[r] * rs; a1[r] = e1[r] * rs;
      Sacc[0][r] += a0[r]; Sacc[1][r] += a1[r];
    }
    int off = (nt * 16 + rlo) * 34;
    unsigned int w00 = (unsigned int)f2bf(a0[0]) | ((unsigned int)f2bf(a0[1]) << 16);
    unsigned int w01 = (unsigned int)f2bf(a0[2]) | ((unsigned int)f2bf(a0[3]) << 16);
    unsigned int w10 = (unsigned int)f2bf(a1[0]) | ((unsigned int)f2bf(a1[1]) << 16);
    unsigned int w11 = (unsigned int)f2bf(a1[2]) | ((unsigned int)f2bf(a1[3]) << 16);
    *(unsigned int*)(&P[wave][off + half * 4])          = w00;
    *(unsigned int*)(&P[wave][off + half * 4 + 2])      = w01;
    *(unsigned int*)(&P[wave][off + 16 + half * 4])     = w10;
    *(unsigned int*)(&P[wave][off + 16 + half * 4 + 2]) = w11;
    if (last) {
      float vl[4];
#pragma unroll
      for (int r = 0; r < 4; ++r) {
        vl[r] = a0[r] + a1[r];
        vl[r] += __shfl_xor(vl[r], 32);
      }
      if (half < 2) {
        long tt = (long)b * NKV + t0 + nt * 16 + rlo;
#pragma unroll
        for (int r = 0; r < 4; ++r) vis[tt * 8 + (half & 1) * 4 + r] = vl[r];
      }
    }
  }
#pragma unroll
  for (int m = 0; m < 2; ++m)
#pragma unroll
    for (int r = 0; r < 4; ++r) {
      Sacc[m][r] += __shfl_xor(Sacc[m][r], 1);
      Sacc[m][r] += __shfl_xor(Sacc[m][r], 2);
      Sacc[m][r] += __shfl_xor(Sacc[m][r], 4);
      Sacc[m][r] += __shfl_xor(Sacc[m][r], 8);
    }
  if (rlo == 0) {
#pragma unroll
    for (int m = 0; m < 2; ++m)
#pragma unroll
      for (int r = 0; r < 4; ++r)
        atomicAdd(&Sg[b * 32 + m * 16 + half * 4 + r], Sacc[m][r]);
  }
  short8 pa[2][2];
#pragma unroll
  for (int m = 0; m < 2; ++m)
#pragma unroll
    for (int kc = 0; kc < 2; ++kc) {
      short8 f;
#pragma unroll
      for (int i = 0; i < 8; ++i)
        f[i] = (short)P[wave][(kc * 32 + half * 8 + i) * 34 + m * 16 + rlo];
      pa[m][kc] = f;
    }
  float* Wred = (float*)&P[wave][0];
  int myh = half >> 1;
#pragma unroll
  for (int h = 0; h < 4; ++h) {
    short8 vb0, vb1;
#pragma unroll
    for (int i = 0; i < 8; ++i) {
      vb0[i] = (short)Vs[wave][(half * 8 + i) * 66 + h * 16 + rlo];
      vb1[i] = (short)Vs[wave][(32 + half * 8 + i) * 66 + h * 16 + rlo];
    }
#pragma unroll
    for (int m = 0; m < 2; ++m) {
      f32x4 wacc = {0.f, 0.f, 0.f, 0.f};
      wacc = __builtin_amdgcn_mfma_f32_16x16x32_bf16(pa[m][0], vb0, wacc, 0, 0, 0);
      wacc = __builtin_amdgcn_mfma_f32_16x16x32_bf16(pa[m][1], vb1, wacc, 0, 0, 0);
      if (h == m * 2 + myh) {
#pragma unroll
        for (int r = 0; r < 4; ++r)
          Wred[(m * 16 + half * 4 + r) * 16 + rlo] = wacc[r];
      }
    }
  }
  __syncthreads();
  int tid = threadIdx.x;
#pragma unroll
  for (int r2 = 0; r2 < 2; ++r2) {
    int idx = tid + r2 * 256;
    float v = ((const float*)&P[0][0])[idx] + ((const float*)&P[1][0])[idx] +
              ((const float*)&P[2][0])[idx] + ((const float*)&P[3][0])[idx];
    atomicAdd(&Wg[b * 512 + idx], v);
  }
}

// ---------------------------------------------------------------------------
// K3: coalesced GRU gate loads via transposed weights. grid 512 x 64.
// ---------------------------------------------------------------------------
template <int IT>
__global__ __launch_bounds__(64) void k_update(
    float* __restrict__ Sg, float* __restrict__ Wg,
    float* __restrict__ slots_buf,
    const float* __restrict__ WihT, const float* __restrict__ WhhT,
    const float* __restrict__ b_ih, const float* __restrict__ b_hh,
    const float* __restrict__ g_mlp, const float* __restrict__ b_mlp,
    const float* __restrict__ W1, const float* __restrict__ b1,
    const float* __restrict__ W2, const float* __restrict__ b2,
    const float* __restrict__ g_slot, const float* __restrict__ b_slot,
    const float* __restrict__ Wq, float* __restrict__ qbuf,
    float* __restrict__ out_slots) {
  constexpr int compute_next = (IT < 2);
  constexpr int write_out = (IT == 2);
  int b = blockIdx.x >> 3, s = blockIdx.x & 7, d = threadIdx.x;
  __shared__ float upd_s[64], h_s[64], lnm_s[64], h1_s[128], l2_s[64];
  float hp = slots_buf[(b * 8 + s) * 64 + d];
  int hh = d >> 4, dh = d & 15, hq = hh * 8 + s;
  float denom = Sg[b * 32 + hq] + 8192.f * 1e-8f;
  float updv = Wg[(b * 32 + hq) * 16 + dh] / denom;
  upd_s[d] = updv; h_s[d] = hp;
  __syncthreads();
  float xr = b_ih[d], xz = b_ih[64 + d], xn = b_ih[128 + d];
  float hr = b_hh[d], hz = b_hh[64 + d], hn3 = b_hh[128 + d];
#pragma unroll 8
  for (int j = 0; j < 64; ++j) {
    float uj = upd_s[j], hj = h_s[j];
    xr = fmaf(uj, WihT[j * 192 + d], xr);
    xz = fmaf(uj, WihT[j * 192 + 64 + d], xz);
    xn = fmaf(uj, WihT[j * 192 + 128 + d], xn);
    hr = fmaf(hj, WhhT[j * 192 + d], hr);
    hz = fmaf(hj, WhhT[j * 192 + 64 + d], hz);
    hn3 = fmaf(hj, WhhT[j * 192 + 128 + d], hn3);
  }
  float r = sigm(xr + hr);
  float z = sigm(xz + hz);
  float n = tanhf(xn + r * hn3);
  float hn = (1.f - z) * n + z * hp;
  float sum = hn, sq = hn * hn;
#pragma unroll
  for (int msk = 1; msk < 64; msk <<= 1) { sum += __shfl_xor(sum, msk); sq += __shfl_xor(sq, msk); }
  float mean = sum * 0.015625f, var = sq * 0.015625f - mean * mean;
  float lnv = (hn - mean) * rsqrtf(var + 1e-5f) * g_mlp[d] + b_mlp[d];
  lnm_s[d] = lnv;
  __syncthreads();
  float a1a = b1[d], a1b = b1[64 + d];
#pragma unroll 8
  for (int j = 0; j < 64; ++j) {
    float lj = lnm_s[j];
    a1a = fmaf(lj, W1[j * 128 + d], a1a);
    a1b = fmaf(lj, W1[j * 128 + 64 + d], a1b);
  }
  h1_s[d] = fmaxf(a1a, 0.f); h1_s[64 + d] = fmaxf(a1b, 0.f);
  __syncthreads();
  float a2 = b2[d];
#pragma unroll 8
  for (int c = 0; c < 128; ++c) a2 = fmaf(h1_s[c], W2[c * 64 + d], a2);
  float outv = hn + a2;
  slots_buf[(b * 8 + s) * 64 + d] = outv;
  if (write_out) out_slots[(b * 8 + s) * 64 + d] = outv;
  if (compute_next) {
    float sum2 = outv, sq2 = outv * outv;
#pragma unroll
    for (int msk = 1; msk < 64; msk <<= 1) { sum2 += __shfl_xor(sum2, msk); sq2 += __shfl_xor(sq2, msk); }
    float mean2 = sum2 * 0.015625f, var2 = sq2 * 0.015625f - mean2 * mean2;
    float l2 = (outv - mean2) * rsqrtf(var2 + 1e-5f) * g_slot[d] + b_slot[d];
    l2_s[d] = l2;
    __syncthreads();
    float acc = 0.f;
#pragma unroll 8
    for (int j = 0; j < 64; ++j) acc = fmaf(l2_s[j], Wq[j * 64 + d], acc);
    acc *= 0.25f;
    qbuf[(b * 32 + hq) * 16 + dh] = acc;
    if (d < 4) Sg[b * 32 + d * 8 + s] = 0.f;
    Wg[(b * 32 + hq) * 16 + dh] = 0.f;
  }
}

extern "C" void kernel_launch(void* const* d_in, const int* in_sizes, int n_in,
                              void* d_out, int out_size, void* d_ws, size_t ws_size,
                              hipStream_t stream) {
  const float* inputs    = (const float*)d_in[0];
  const float* slots     = (const float*)d_in[1];
  const float* ln_in_g   = (const float*)d_in[2];
  const float* ln_in_b   = (const float*)d_in[3];
  const float* ln_slot_g = (const float*)d_in[4];
  const float* ln_slot_b = (const float*)d_in[5];
  const float* ln_mlp_g  = (const float*)d_in[6];
  const float* ln_mlp_b  = (const float*)d_in[7];
  const float* Wq        = (const float*)d_in[8];
  const float* Wk        = (const float*)d_in[9];
  const float* Wv        = (const float*)d_in[10];
  const float* W_ih      = (const float*)d_in[11];
  const float* W_hh      = (const float*)d_in[12];
  const float* b_ih      = (const float*)d_in[13];
  const float* b_hh      = (const float*)d_in[14];
  const float* mlp_W1    = (const float*)d_in[15];
  const float* mlp_b1    = (const float*)d_in[16];
  const float* mlp_W2    = (const float*)d_in[17];
  const float* mlp_b2    = (const float*)d_in[18];

  float* out_slots = (float*)d_out;                 // [64*8*64]
  float* out_vis   = out_slots + 64 * 8 * 64;       // [64*8192*8]

  char* ws = (char*)d_ws;
  unsigned short* kv = (unsigned short*)ws;         // 128 MiB
  size_t off = (size_t)64 * 8192 * 128 * 2;
  float* qbuf      = (float*)(ws + off); off += (size_t)64 * 32 * 16 * 4;
  float* Sg        = (float*)(ws + off); off += (size_t)64 * 32 * 4;
  float* Wg        = (float*)(ws + off); off += (size_t)64 * 512 * 4;
  float* slots_buf = (float*)(ws + off); off += (size_t)64 * 512 * 4;
  unsigned short* wf = (unsigned short*)(ws + off); off += (size_t)1024 * 8 * 2;
  float* WihT = (float*)(ws + off); off += (size_t)192 * 64 * 4;
  float* WhhT = (float*)(ws + off); off += (size_t)192 * 64 * 4;

  hipLaunchKernelGGL(k_prep0, dim3(52), dim3(256), 0, stream,
                     Wk, Wv, W_ih, W_hh, wf, WihT, WhhT);
  hipLaunchKernelGGL(k_proj, dim3(2048), dim3(256), 0, stream,
                     inputs, ln_in_g, ln_in_b, wf, kv, 0L);
  hipLaunchKernelGGL(k_proj, dim3(2048), dim3(256), 0, stream,
                     inputs, ln_in_g, ln_in_b, wf, kv, (long)NB * NKV / 2);
  hipLaunchKernelGGL(k_prep, dim3(512), dim3(64), 0, stream,
                     slots, ln_slot_g, ln_slot_b, Wq, slots_buf, qbuf, Sg, Wg);

  hipLaunchKernelGGL((k_attn<0>), dim3(64 * 32), dim3(256), 0, stream,
                     kv, qbuf, Sg, Wg, out_vis);
  hipLaunchKernelGGL((k_update<0>), dim3(512), dim3(64), 0, stream,
                     Sg, Wg, slots_buf, WihT, WhhT, b_ih, b_hh,
                     ln_mlp_g, ln_mlp_b, mlp_W1, mlp_b1, mlp_W2, mlp_b2,
                     ln_slot_g, ln_slot_b, Wq, qbuf, out_slots);
  hipLaunchKernelGGL((k_attn<1>), dim3(64 * 32), dim3(256), 0, stream,
                     kv, qbuf, Sg, Wg, out_vis);
  hipLaunchKernelGGL((k_update<1>), dim3(512), dim3(64), 0, stream,
                     Sg, Wg, slots_buf, WihT, WhhT, b_ih, b_hh,
                     ln_mlp_g, ln_mlp_b, mlp_W1, mlp_b1, mlp_W2, mlp_b2,
                     ln_slot_g, ln_slot_b, Wq, qbuf, out_slots);
  hipLaunchKernelGGL((k_attn<2>), dim3(64 * 32), dim3(256), 0, stream,
                     kv, qbuf, Sg, Wg, out_vis);
  hipLaunchKernelGGL((k_update<2>), dim3(512), dim3(64), 0, stream,
                     Sg, Wg, slots_buf, WihT, WhhT, b_ih, b_hh,
                     ln_mlp_g, ln_mlp_b, mlp_W1, mlp_b1, mlp_W2, mlp_b2,
                     ln_slot_g, ln_slot_b, Wq, qbuf, out_slots);
}